// Round 9
// baseline (3571.001 us; speedup 1.0000x reference)
//
#include <hip/hip_runtime.h>
#include <math.h>

#define N_ANCHORS 2048
#define THRESH 0.3f
#define OVERLAP 0.5f
#define NBC 32

#define TRI(k, w) ((k) * ((k) + 1) / 2 + (w))   // triangular row storage

// ---- per-bc workspace layout (bytes) ----
#define WOFF_CSC   0        // float[2048]   score, compacted (anchor order)
#define WOFF_CBX   8192     // float2[2048]  box,   compacted
#define WOFF_CID   24576    // ushort[2048]  anchor id, compacted
#define WOFF_SBOX  28672    // float2[2048]  box, sorted order
#define WOFF_SSC   45056    // float[2048]   score, sorted order
#define WOFF_SID   53248    // ushort[2048]  anchor id, sorted order
#define WOFF_MAT   57344    // u64[36*64]    triangular suppression matrix
#define WS_PER_BC  75776
#define WOFF_V     ((size_t)NBC * WS_PER_BC)    // int[32]
#define WS_NEED    (WOFF_V + 128)

// ============================ K1: decode + compact ============================
__global__ __launch_bounds__(512) void k1_decode(
    const float* __restrict__ loc, const float* __restrict__ cls,
    const float* __restrict__ defs, float* __restrict__ out,
    unsigned char* __restrict__ ws)
{
#pragma clang fp contract(off)
    const int tid = threadIdx.x, lane = tid & 63, wid = tid >> 6;
    const int bc = blockIdx.x, b = bc >> 2, c = bc & 3;
    __shared__ int s_wsum[8], s_woff[8];

    // zero output (fire-and-forget within this kernel)
    float* outb = out + (size_t)bc * N_ANCHORS * 3;
    {
        float4 z4 = make_float4(0.f, 0.f, 0.f, 0.f);
        float4* ob4 = (float4*)outb;
        for (int i = tid; i < (N_ANCHORS * 3) / 4; i += 512) ob4[i] = z4;
    }

    // decode + softmax, 4 consecutive anchors per thread
    const int base = tid * 4;
    float c20[20], l8v[8], d8v[8];
    {
        const float4* cp4 = (const float4*)(cls + ((size_t)b * N_ANCHORS + base) * 5);
#pragma unroll
        for (int q = 0; q < 5; ++q) ((float4*)c20)[q] = cp4[q];
        const float4* lp4 = (const float4*)(loc + ((size_t)b * N_ANCHORS + base) * 2);
        ((float4*)l8v)[0] = lp4[0]; ((float4*)l8v)[1] = lp4[1];
        const float4* dp4 = (const float4*)(defs + (size_t)base * 2);
        ((float4*)d8v)[0] = dp4[0]; ((float4*)d8v)[1] = dp4[1];
    }
    float sc4[4], bs4[4], be4[4];
    int vmask = 0, cnt = 0;
#pragma unroll
    for (int k = 0; k < 4; ++k) {
        float x0 = c20[5*k+0], x1 = c20[5*k+1], x2 = c20[5*k+2],
              x3 = c20[5*k+3], x4 = c20[5*k+4];
        float m  = fmaxf(fmaxf(fmaxf(fmaxf(x0, x1), x2), x3), x4);
        float e0 = expf(x0 - m), e1 = expf(x1 - m), e2 = expf(x2 - m),
              e3 = expf(x3 - m), e4 = expf(x4 - m);
        float sum = e0 + e1 + e2 + e3 + e4;
        float ec  = (c == 0) ? e1 : (c == 1) ? e2 : (c == 2) ? e3 : e4;
        float score = ec / sum;
        float l0 = l8v[2*k], l1 = l8v[2*k+1];
        float d0 = d8v[2*k], d1 = d8v[2*k+1];
        float cc = d0 + l0 * d1;
        float w  = d1 * expf(l1);
        sc4[k] = score;
        bs4[k] = cc - 0.5f * w;
        be4[k] = cc + 0.5f * w;
        if (score > THRESH) { vmask |= (1 << k); cnt++; }
    }

    // ordered compaction (compacted order == anchor order == tie-break order)
    int inc = cnt;
    for (int d = 1; d < 64; d <<= 1) {
        int v = __shfl_up(inc, d);
        if (lane >= d) inc += v;
    }
    if (lane == 63) s_wsum[wid] = inc;
    __syncthreads();
    if (tid == 0) {
        int o = 0;
        for (int w = 0; w < 8; ++w) { s_woff[w] = o; o += s_wsum[w]; }
        ((int*)(ws + WOFF_V))[bc] = o;
    }
    __syncthreads();
    float*          wcsc = (float*)(ws + (size_t)bc * WS_PER_BC + WOFF_CSC);
    float2*         wcbx = (float2*)(ws + (size_t)bc * WS_PER_BC + WOFF_CBX);
    unsigned short* wcid = (unsigned short*)(ws + (size_t)bc * WS_PER_BC + WOFF_CID);
    int off = s_woff[wid] + (inc - cnt);
#pragma unroll
    for (int k = 0; k < 4; ++k) {
        if (vmask & (1 << k)) {
            wcsc[off] = sc4[k];
            wcbx[off] = make_float2(bs4[k], be4[k]);
            wcid[off] = (unsigned short)(base + k);
            off++;
        }
    }
}

// ===================== K2: counting rank (64 candidates/block) =====================
// rank(q) = #{i<V : s_i > s_q  or (s_i == s_q and i < q)} — stable argsort order.
// Ranks are a permutation -> scatter writes are race-free across blocks.
__global__ __launch_bounds__(256) void k2_rank(unsigned char* __restrict__ ws)
{
    const int bx = blockIdx.x;
    const int bc = bx >> 5, j = bx & 31;
    const int V = ((const int*)(ws + WOFF_V))[bc];
    if ((j << 6) >= V) return;
    const unsigned char* wsb = ws + (size_t)bc * WS_PER_BC;
    const float*          csc = (const float*)(wsb + WOFF_CSC);
    const float2*         cbx = (const float2*)(wsb + WOFF_CBX);
    const unsigned short* cid = (const unsigned short*)(wsb + WOFF_CID);
    float2*         sbox = (float2*)(wsb + WOFF_SBOX);
    float*          ssc  = (float*)(wsb + WOFF_SSC);
    unsigned short* sid  = (unsigned short*)(wsb + WOFF_SID);

    const int tid = threadIdx.x, lane = tid & 63, seg = tid >> 6;
    const int q = (j << 6) + lane;
    const bool aq = q < V;
    float m = aq ? csc[q] : INFINITY;
    const int Q = (V + 3) >> 2;
    int i0 = seg * Q, i1 = i0 + Q;
    if (i1 > V) i1 = V;
    int r = 0;
#pragma unroll 4
    for (int i = i0; i < i1; ++i) {        // wave-uniform stream -> scalar loads
        float s = csc[i];
        r += (s > m || (s == m && i < q)) ? 1 : 0;
    }
    __shared__ int part[256];
    part[tid] = r;
    __syncthreads();
    if (seg == 0 && aq) {
        int R = part[lane] + part[64 + lane] + part[128 + lane] + part[192 + lane];
        sbox[R] = cbx[q];
        ssc[R]  = m;
        sid[R]  = cid[q];
    }
}

// ================= K3: suppression matrix build (stripe k per block) =================
__global__ __launch_bounds__(512) void k3_build(unsigned char* __restrict__ ws)
{
#pragma clang fp contract(off)
    const int bx = blockIdx.x;
    const int bc = bx >> 3, k = bx & 7;
    const int V = ((const int*)(ws + WOFF_V))[bc];
    if ((k << 6) >= V || V > 512) return;   // V>512 handled by K4 fallback
    const int tid = threadIdx.x, lane = tid & 63, w = tid >> 6;
    if (w > k) return;                       // waves beyond stripe idle
    const unsigned char* wsb = ws + (size_t)bc * WS_PER_BC;
    const float2* sbox = (const float2*)(wsb + WOFF_SBOX);
    unsigned long long* mat = (unsigned long long*)(wsb + WOFF_MAT);

    const int u = (k << 6) + lane;           // sorted row this lane builds
    float2 ub = (u < V) ? sbox[u] : make_float2(1e30f, 1e30f);
    float  ul = ub.y - ub.x;
    const float4* sb4 = (const float4*)(sbox + (w << 6));
    unsigned long long word = 0ull;
    for (int jj = 0; jj < 32; ++jj) {        // rolled: compact code, s_load stream
        float4 bp = sb4[jj];
        float in0 = fmaxf(fminf(ub.y, bp.y) - fmaxf(ub.x, bp.x), 0.0f);
        float un0 = (bp.y - bp.x) + ul - in0;
        float io0 = in0 / fmaxf(un0, 1e-12f);
        float in1 = fmaxf(fminf(ub.y, bp.w) - fmaxf(ub.x, bp.z), 0.0f);
        float un1 = (bp.w - bp.z) + ul - in1;
        float io1 = in1 / fmaxf(un1, 1e-12f);
        if (io0 > OVERLAP) word |= (1ull << (2 * jj));
        if (io1 > OVERLAP) word |= (1ull << (2 * jj + 1));
    }
    if (w == k) word &= (1ull << lane) - 1ull;           // diagonal: only j < u
    { int rem = V - (w << 6); if (rem < 64) word &= (1ull << rem) - 1ull; }
    if (u >= V) word = 0ull;
    mat[(TRI(k, w) << 6) + lane] = word;
}

// ==================== K4: greedy fixpoint + output scatter ====================
__global__ __launch_bounds__(512) void k4_nms(
    float* __restrict__ out, unsigned char* __restrict__ ws)
{
#pragma clang fp contract(off)
    const int tid = threadIdx.x, lane = tid & 63;
    const int bc = blockIdx.x;
    const int V = ((const int*)(ws + WOFF_V))[bc];
    const unsigned char* wsb = ws + (size_t)bc * WS_PER_BC;
    const float2*         sbox = (const float2*)(wsb + WOFF_SBOX);
    const float*          ssc  = (const float*)(wsb + WOFF_SSC);
    const unsigned short* sid  = (const unsigned short*)(wsb + WOFF_SID);
    const unsigned long long* mat = (const unsigned long long*)(wsb + WOFF_MAT);
    __shared__ unsigned long long keptw[32];

    if (V <= 512) {
        if (tid < 64) {
            unsigned long long row[36];
#pragma unroll
            for (int k = 0; k < 8; ++k)
#pragma unroll
                for (int w = 0; w <= k; ++w)
                    row[TRI(k, w)] = mat[(TRI(k, w) << 6) + lane];
            unsigned long long kv[8];
#pragma unroll
            for (int w = 0; w < 8; ++w) {
                kv[w] = 0ull;
                if ((w << 6) < V) {
                    bool dl = false;
#pragma unroll
                    for (int w2 = 0; w2 < w; ++w2)
                        dl |= (row[TRI(w, w2)] & kv[w2]) != 0ull;
                    const unsigned long long rself = row[TRI(w, w)];
                    int rem = V - (w << 6);
                    unsigned long long valid =
                        (rem >= 64) ? ~0ull : ((1ull << rem) - 1ull);
                    unsigned long long cand = valid & ~__ballot(dl);
                    unsigned long long kw = 0ull;
                    while (cand) {
                        unsigned long long suppw = __ballot((rself & cand) != 0ull);
                        unsigned long long nk = cand & ~suppw;
                        if (!nk) nk = cand & (~cand + 1ull);  // acyclic: unreachable
                        kw |= nk;
                        unsigned long long ddw = __ballot((rself & nk) != 0ull);
                        cand &= ~(nk | ddw);
                    }
                    kv[w] = kw;
                }
            }
            if (lane == 0) {
#pragma unroll
                for (int w = 0; w < 8; ++w) keptw[w] = kv[w];
                for (int w = 8; w < 32; ++w) keptw[w] = 0ull;
            }
        }
    } else {
        // exact serial fallback (never taken for this input: V ~ 450)
        if (tid == 0) {
            for (int w = 0; w < 32; ++w) keptw[w] = 0ull;
            for (int i = 0; i < V; ++i) {
                float2 bi = sbox[i];
                float  li = bi.y - bi.x;
                bool sup = false;
                for (int w = 0; w <= (i >> 6) && !sup; ++w) {
                    unsigned long long kw = keptw[w];
                    while (kw && !sup) {
                        int jb = __builtin_ctzll(kw); kw &= kw - 1ull;
                        int jp = (w << 6) + jb;        // kept => jp < i
                        float2 bj = sbox[jp];
                        float in = fmaxf(fminf(bi.y, bj.y) - fmaxf(bi.x, bj.x), 0.0f);
                        float un = (bj.y - bj.x) + li - in;
                        sup = (in / fmaxf(un, 1e-12f)) > OVERLAP;
                    }
                }
                if (!sup) keptw[i >> 6] |= (1ull << (i & 63));
            }
        }
    }
    __syncthreads();

    float* outb = out + (size_t)bc * N_ANCHORS * 3;
    for (int r = tid; r < V; r += 512) {
        if ((keptw[r >> 6] >> (r & 63)) & 1ull) {
            float2 bx = sbox[r];
            if (bx.x > -10.0f && bx.y < 10.0f) {
                int n = sid[r];
                float* o = outb + (size_t)n * 3;
                o[0] = bx.x;
                o[1] = bx.y;
                o[2] = ssc[r];
            }
        }
    }
}

// =============== fallback: R7 monolithic kernel (if ws too small) ===============
#define BLOCK 512
#define OFF_CSC   0
#define OFF_CBX   8208
#define OFF_CID   24592
#define OFF_SBOX  0
#define OFF_SSC   16896
#define OFF_SID   25088
#define POOL_SZ   29184

__global__ __launch_bounds__(BLOCK) void det_mono(
    const float* __restrict__ loc, const float* __restrict__ cls,
    const float* __restrict__ defs, float* __restrict__ out)
{
#pragma clang fp contract(off)
    const int tid  = threadIdx.x;
    const int lane = tid & 63;
    const int wid  = tid >> 6;
    const int bc   = blockIdx.x;
    const int b    = bc >> 2;
    const int c    = bc & 3;

    __shared__ __align__(16) unsigned char pool[POOL_SZ];
    __shared__ __align__(16) unsigned long long suprowT[8 * 512];
    __shared__ unsigned long long keptg[32];
    __shared__ unsigned long long s_deadw[8];
    __shared__ int s_wsum[8], s_woff[8], s_V;

    float*          csc  = (float*)(pool + OFF_CSC);
    float2*         cbx  = (float2*)(pool + OFF_CBX);
    unsigned short* cid  = (unsigned short*)(pool + OFF_CID);
    float2*         sbox = (float2*)(pool + OFF_SBOX);
    float*          ssc  = (float*)(pool + OFF_SSC);
    unsigned short* sid  = (unsigned short*)(pool + OFF_SID);

    float* const outb = out + (size_t)bc * N_ANCHORS * 3;
    {
        float4 z4 = make_float4(0.f, 0.f, 0.f, 0.f);
        float4* ob4 = (float4*)outb;
        for (int i = tid; i < (N_ANCHORS * 3) / 4; i += BLOCK) ob4[i] = z4;
    }
    if (tid < 32) keptg[tid] = 0ull;

    const int base = tid * 4;
    float c20[20], l8v[8], d8v[8];
    {
        const float4* cp4 = (const float4*)(cls + ((size_t)b * N_ANCHORS + base) * 5);
#pragma unroll
        for (int q = 0; q < 5; ++q) ((float4*)c20)[q] = cp4[q];
        const float4* lp4 = (const float4*)(loc + ((size_t)b * N_ANCHORS + base) * 2);
        ((float4*)l8v)[0] = lp4[0]; ((float4*)l8v)[1] = lp4[1];
        const float4* dp4 = (const float4*)(defs + (size_t)base * 2);
        ((float4*)d8v)[0] = dp4[0]; ((float4*)d8v)[1] = dp4[1];
    }
    float sc4[4], bs4[4], be4[4];
    int vmask = 0, cnt = 0;
#pragma unroll
    for (int k = 0; k < 4; ++k) {
        float x0 = c20[5*k+0], x1 = c20[5*k+1], x2 = c20[5*k+2],
              x3 = c20[5*k+3], x4 = c20[5*k+4];
        float m  = fmaxf(fmaxf(fmaxf(fmaxf(x0, x1), x2), x3), x4);
        float e0 = expf(x0 - m), e1 = expf(x1 - m), e2 = expf(x2 - m),
              e3 = expf(x3 - m), e4 = expf(x4 - m);
        float sum = e0 + e1 + e2 + e3 + e4;
        float ec  = (c == 0) ? e1 : (c == 1) ? e2 : (c == 2) ? e3 : e4;
        float score = ec / sum;
        float l0 = l8v[2*k], l1 = l8v[2*k+1];
        float d0 = d8v[2*k], d1 = d8v[2*k+1];
        float cc = d0 + l0 * d1;
        float w  = d1 * expf(l1);
        sc4[k] = score;
        bs4[k] = cc - 0.5f * w;
        be4[k] = cc + 0.5f * w;
        if (score > THRESH) { vmask |= (1 << k); cnt++; }
    }

    int inc = cnt;
    for (int d = 1; d < 64; d <<= 1) {
        int v = __shfl_up(inc, d);
        if (lane >= d) inc += v;
    }
    if (lane == 63) s_wsum[wid] = inc;
    __syncthreads();
    if (tid == 0) {
        int o = 0;
        for (int w = 0; w < 8; ++w) { s_woff[w] = o; o += s_wsum[w]; }
        s_V = o;
    }
    __syncthreads();
    {
        int off = s_woff[wid] + (inc - cnt);
#pragma unroll
        for (int k = 0; k < 4; ++k) {
            if (vmask & (1 << k)) {
                csc[off] = sc4[k];
                cbx[off] = make_float2(bs4[k], be4[k]);
                cid[off] = (unsigned short)(base + k);
                off++;
            }
        }
    }
    __syncthreads();
    const int V = s_V;
    const int SCend = ((V + 511) >> 9) << 9;
    if (tid < 4) csc[V + tid] = -INFINITY;
    __syncthreads();

#define RANKCMP(sv, ib, off2, mref, rref)                                   \
    rref += ((sv) > (mref) || ((sv) == (mref) && (ib) + (off2) < pcmp)) ? 1 : 0;
    int rr[4]; float2 rb[4]; float rs[4]; int ridv[4]; int nown = 0;
    if (V <= 512) {
        if (tid < 256) {
            int   p0 = tid, p1 = tid + 256;
            bool  a0 = p0 < V, a1 = p1 < V;
            float m0 = a0 ? csc[p0] : INFINITY;
            float m1 = a1 ? csc[p1] : INFINITY;
            int   r0 = 0, r1 = 0;
            const float4* cs4 = (const float4*)csc;
            const int n4 = (V + 3) >> 2;
            for (int i4 = 0; i4 < n4; ++i4) {
                float4 s4 = cs4[i4];
                int ib = i4 << 2;
                { int pcmp = p0;
                  RANKCMP(s4.x, ib, 0, m0, r0) RANKCMP(s4.y, ib, 1, m0, r0)
                  RANKCMP(s4.z, ib, 2, m0, r0) RANKCMP(s4.w, ib, 3, m0, r0) }
                { int pcmp = p1;
                  RANKCMP(s4.x, ib, 0, m1, r1) RANKCMP(s4.y, ib, 1, m1, r1)
                  RANKCMP(s4.z, ib, 2, m1, r1) RANKCMP(s4.w, ib, 3, m1, r1) }
            }
            if (a0) { rr[nown] = r0; rb[nown] = cbx[p0]; rs[nown] = m0; ridv[nown] = cid[p0]; nown++; }
            if (a1) { rr[nown] = r1; rb[nown] = cbx[p1]; rs[nown] = m1; ridv[nown] = cid[p1]; nown++; }
        }
    } else {
        for (int p = tid; p < V; p += BLOCK) {
            float s = csc[p];
            int r = 0;
            const float4* cs4 = (const float4*)csc;
            const int n4 = (V + 3) >> 2;
            for (int i4 = 0; i4 < n4; ++i4) {
                float4 s4 = cs4[i4];
                int ib = i4 << 2;
                int pcmp = p;
                RANKCMP(s4.x, ib, 0, s, r) RANKCMP(s4.y, ib, 1, s, r)
                RANKCMP(s4.z, ib, 2, s, r) RANKCMP(s4.w, ib, 3, s, r)
            }
            rr[nown] = r; rb[nown] = cbx[p]; rs[nown] = s; ridv[nown] = cid[p]; nown++;
        }
    }
#undef RANKCMP
    __syncthreads();
    for (int q = 0; q < nown; ++q) {
        sbox[rr[q]] = rb[q];
        ssc[rr[q]]  = rs[q];
        sid[rr[q]]  = (unsigned short)ridv[q];
    }
    for (int i = V + tid; i < SCend; i += BLOCK)
        sbox[i] = make_float2(1e30f, 1e30f);
    __syncthreads();

    for (int s0 = 0; s0 < V; s0 += 512) {
        const int scn = (V - s0 < 512) ? (V - s0) : 512;
        const int i   = tid;
        float2 my = sbox[s0 + i];
        float  ml = my.y - my.x;

        bool dead = false;
        const int ew_n = s0 >> 6;
        for (int ew = 0; ew < ew_n; ++ew) {
            unsigned long long kw = keptg[ew];
            if (kw) {
                const float4* sb4 = (const float4*)(sbox + (ew << 6));
#pragma unroll
                for (int jj = 0; jj < 32; ++jj) {
                    float4 bp = sb4[jj];
                    float in0 = fmaxf(fminf(my.y, bp.y) - fmaxf(my.x, bp.x), 0.0f);
                    float un0 = (bp.y - bp.x) + ml - in0;
                    float io0 = in0 / fmaxf(un0, 1e-12f);
                    float in1 = fmaxf(fminf(my.y, bp.w) - fmaxf(my.x, bp.z), 0.0f);
                    float un1 = (bp.w - bp.z) + ml - in1;
                    float io1 = in1 / fmaxf(un1, 1e-12f);
                    unsigned long long bits = kw >> (2 * jj);
                    dead |= (io0 > OVERLAP) && ((bits & 1ull) != 0ull);
                    dead |= (io1 > OVERLAP) && ((bits & 2ull) != 0ull);
                }
            }
        }
        {
            unsigned long long db = __ballot(dead && (i < scn));
            if (lane == 0) s_deadw[wid] = db;
        }

        {
            int t = 0;
#pragma unroll
            for (int k = 0; k < 8; ++k) {
#pragma unroll
                for (int w = 0; w <= k; ++w, ++t) {
                    if ((t & 7) == wid) {
                        const int u = (k << 6) + lane;
                        float2 ub = sbox[s0 + u];
                        float  ul = ub.y - ub.x;
                        const float4* sb4 = (const float4*)(sbox + s0 + (w << 6));
                        unsigned long long word = 0ull;
                        if (w == k) {
#pragma unroll
                            for (int jj = 0; jj < 32; ++jj) {
                                float4 bp = sb4[jj];
                                float in0 = fmaxf(fminf(ub.y, bp.y) - fmaxf(ub.x, bp.x), 0.0f);
                                float un0 = (bp.y - bp.x) + ul - in0;
                                float io0 = in0 / fmaxf(un0, 1e-12f);
                                float in1 = fmaxf(fminf(ub.y, bp.w) - fmaxf(ub.x, bp.z), 0.0f);
                                float un1 = (bp.w - bp.z) + ul - in1;
                                float io1 = in1 / fmaxf(un1, 1e-12f);
                                if (io0 > OVERLAP && 2 * jj     < lane) word |= (1ull << (2 * jj));
                                if (io1 > OVERLAP && 2 * jj + 1 < lane) word |= (1ull << (2 * jj + 1));
                            }
                        } else {
#pragma unroll
                            for (int jj = 0; jj < 32; ++jj) {
                                float4 bp = sb4[jj];
                                float in0 = fmaxf(fminf(ub.y, bp.y) - fmaxf(ub.x, bp.x), 0.0f);
                                float un0 = (bp.y - bp.x) + ul - in0;
                                float io0 = in0 / fmaxf(un0, 1e-12f);
                                float in1 = fmaxf(fminf(ub.y, bp.w) - fmaxf(ub.x, bp.z), 0.0f);
                                float un1 = (bp.w - bp.z) + ul - in1;
                                float io1 = in1 / fmaxf(un1, 1e-12f);
                                if (io0 > OVERLAP) word |= (1ull << (2 * jj));
                                if (io1 > OVERLAP) word |= (1ull << (2 * jj + 1));
                            }
                        }
                        suprowT[(w << 9) + u] = word;
                    }
                }
            }
        }
        __syncthreads();

        if (wid == 0) {
            unsigned long long row[36];
#pragma unroll
            for (int k = 0; k < 8; ++k)
#pragma unroll
                for (int w = 0; w <= k; ++w)
                    row[TRI(k, w)] = suprowT[(w << 9) + (k << 6) + lane];
            unsigned long long sdead[8];
#pragma unroll
            for (int w = 0; w < 8; ++w) sdead[w] = s_deadw[w];

            unsigned long long kv[8];
#pragma unroll
            for (int w = 0; w < 8; ++w) {
                kv[w] = 0ull;
                if ((w << 6) < scn) {
                    bool dl = ((sdead[w] >> lane) & 1ull) != 0ull;
#pragma unroll
                    for (int w2 = 0; w2 < w; ++w2)
                        dl |= (row[TRI(w, w2)] & kv[w2]) != 0ull;
                    const unsigned long long rself = row[TRI(w, w)];
                    int rem = scn - (w << 6);
                    unsigned long long valid =
                        (rem >= 64) ? ~0ull : ((1ull << rem) - 1ull);
                    unsigned long long cand = valid & ~__ballot(dl);
                    unsigned long long kw = 0ull;
                    while (cand) {
                        unsigned long long suppw = __ballot((rself & cand) != 0ull);
                        unsigned long long nk = cand & ~suppw;
                        if (!nk) nk = cand & (~cand + 1ull);
                        kw |= nk;
                        unsigned long long ddw = __ballot((rself & nk) != 0ull);
                        cand &= ~(nk | ddw);
                    }
                    kv[w] = kw;
                }
            }
            if (lane == 0) {
#pragma unroll
                for (int w = 0; w < 8; ++w) keptg[(s0 >> 6) + w] |= kv[w];
            }
        }
        __syncthreads();
    }

    for (int r = tid; r < V; r += BLOCK) {
        if ((keptg[r >> 6] >> (r & 63)) & 1ull) {
            float2 bx = sbox[r];
            if (bx.x > -10.0f && bx.y < 10.0f) {
                int n = sid[r];
                float* o = outb + (size_t)n * 3;
                o[0] = bx.x;
                o[1] = bx.y;
                o[2] = ssc[r];
            }
        }
    }
}

extern "C" void kernel_launch(void* const* d_in, const int* in_sizes, int n_in,
                              void* d_out, int out_size, void* d_ws, size_t ws_size,
                              hipStream_t stream) {
    const float* loc  = (const float*)d_in[0];  // localizations (8,2048,2)
    const float* cls  = (const float*)d_in[1];  // classifications (8,2048,5)
    const float* defs = (const float*)d_in[2];  // localizations_default (2048,2)
    float* out = (float*)d_out;                 // (8,4,2048,3) fp32
    if (ws_size >= WS_NEED) {
        unsigned char* ws = (unsigned char*)d_ws;
        k1_decode<<<NBC, 512, 0, stream>>>(loc, cls, defs, out, ws);
        k2_rank  <<<NBC * 32, 256, 0, stream>>>(ws);
        k3_build <<<NBC * 8, 512, 0, stream>>>(ws);
        k4_nms   <<<NBC, 512, 0, stream>>>(out, ws);
    } else {
        det_mono<<<NBC, BLOCK, 0, stream>>>(loc, cls, defs, out);
    }
}

// Round 10
// 150.817 us; speedup vs baseline: 23.6777x; 23.6777x over previous
//
#include <hip/hip_runtime.h>
#include <math.h>

#define N_ANCHORS 2048
#define THRESH 0.3f
#define OVERLAP 0.5f
#define NBC 32

#define TRI(k, w) ((k) * ((k) + 1) / 2 + (w))   // triangular row storage

// ---- per-bc workspace layout (bytes) ----
#define WOFF_CSC   0        // float[2048]   score, compacted (anchor order)
#define WOFF_CBX   8192     // float2[2048]  box,   compacted
#define WOFF_CID   24576    // ushort[2048]  anchor id, compacted
#define WOFF_SBOX  28672    // float2[2048]  box, sorted order
#define WOFF_SSC   45056    // float[2048]   score, sorted order
#define WOFF_SID   53248    // ushort[2048]  anchor id, sorted order
#define WOFF_MAT   57344    // u64[36*64]    triangular matrix, superchunk 0
#define WS_PER_BC  75776
#define WOFF_V     ((size_t)NBC * WS_PER_BC)    // int[32]
#define WS_NEED    (WOFF_V + 128)

// ============================ K1: decode + compact ============================
__global__ __launch_bounds__(512) void k1_decode(
    const float* __restrict__ loc, const float* __restrict__ cls,
    const float* __restrict__ defs, float* __restrict__ out,
    unsigned char* __restrict__ ws)
{
#pragma clang fp contract(off)
    const int tid = threadIdx.x, lane = tid & 63, wid = tid >> 6;
    const int bc = blockIdx.x, b = bc >> 2, c = bc & 3;
    __shared__ int s_wsum[8], s_woff[8];

    // zero output (fire-and-forget within this kernel)
    float* outb = out + (size_t)bc * N_ANCHORS * 3;
    {
        float4 z4 = make_float4(0.f, 0.f, 0.f, 0.f);
        float4* ob4 = (float4*)outb;
        for (int i = tid; i < (N_ANCHORS * 3) / 4; i += 512) ob4[i] = z4;
    }

    // decode + softmax, 4 consecutive anchors per thread
    const int base = tid * 4;
    float c20[20], l8v[8], d8v[8];
    {
        const float4* cp4 = (const float4*)(cls + ((size_t)b * N_ANCHORS + base) * 5);
#pragma unroll
        for (int q = 0; q < 5; ++q) ((float4*)c20)[q] = cp4[q];
        const float4* lp4 = (const float4*)(loc + ((size_t)b * N_ANCHORS + base) * 2);
        ((float4*)l8v)[0] = lp4[0]; ((float4*)l8v)[1] = lp4[1];
        const float4* dp4 = (const float4*)(defs + (size_t)base * 2);
        ((float4*)d8v)[0] = dp4[0]; ((float4*)d8v)[1] = dp4[1];
    }
    float sc4[4], bs4[4], be4[4];
    int vmask = 0, cnt = 0;
#pragma unroll
    for (int k = 0; k < 4; ++k) {
        float x0 = c20[5*k+0], x1 = c20[5*k+1], x2 = c20[5*k+2],
              x3 = c20[5*k+3], x4 = c20[5*k+4];
        float m  = fmaxf(fmaxf(fmaxf(fmaxf(x0, x1), x2), x3), x4);
        float e0 = expf(x0 - m), e1 = expf(x1 - m), e2 = expf(x2 - m),
              e3 = expf(x3 - m), e4 = expf(x4 - m);
        float sum = e0 + e1 + e2 + e3 + e4;
        float ec  = (c == 0) ? e1 : (c == 1) ? e2 : (c == 2) ? e3 : e4;
        float score = ec / sum;
        float l0 = l8v[2*k], l1 = l8v[2*k+1];
        float d0 = d8v[2*k], d1 = d8v[2*k+1];
        float cc = d0 + l0 * d1;
        float w  = d1 * expf(l1);
        sc4[k] = score;
        bs4[k] = cc - 0.5f * w;
        be4[k] = cc + 0.5f * w;
        if (score > THRESH) { vmask |= (1 << k); cnt++; }
    }

    // ordered compaction (compacted order == anchor order == tie-break order)
    int inc = cnt;
    for (int d = 1; d < 64; d <<= 1) {
        int v = __shfl_up(inc, d);
        if (lane >= d) inc += v;
    }
    if (lane == 63) s_wsum[wid] = inc;
    __syncthreads();
    if (tid == 0) {
        int o = 0;
        for (int w = 0; w < 8; ++w) { s_woff[w] = o; o += s_wsum[w]; }
        ((int*)(ws + WOFF_V))[bc] = o;
    }
    __syncthreads();
    float*          wcsc = (float*)(ws + (size_t)bc * WS_PER_BC + WOFF_CSC);
    float2*         wcbx = (float2*)(ws + (size_t)bc * WS_PER_BC + WOFF_CBX);
    unsigned short* wcid = (unsigned short*)(ws + (size_t)bc * WS_PER_BC + WOFF_CID);
    int off = s_woff[wid] + (inc - cnt);
#pragma unroll
    for (int k = 0; k < 4; ++k) {
        if (vmask & (1 << k)) {
            wcsc[off] = sc4[k];
            wcbx[off] = make_float2(bs4[k], be4[k]);
            wcid[off] = (unsigned short)(base + k);
            off++;
        }
    }
}

// ===================== K2: counting rank (64 candidates/block) =====================
// rank(q) = #{i<V : s_i > s_q  or (s_i == s_q and i < q)} — stable argsort order.
// Ranks are a permutation -> scatter writes are race-free across blocks.
__global__ __launch_bounds__(256) void k2_rank(unsigned char* __restrict__ ws)
{
    const int bx = blockIdx.x;
    const int bc = bx >> 5, j = bx & 31;
    const int V = ((const int*)(ws + WOFF_V))[bc];
    if ((j << 6) >= V) return;
    const unsigned char* wsb = ws + (size_t)bc * WS_PER_BC;
    const float*          csc = (const float*)(wsb + WOFF_CSC);
    const float2*         cbx = (const float2*)(wsb + WOFF_CBX);
    const unsigned short* cid = (const unsigned short*)(wsb + WOFF_CID);
    float2*         sbox = (float2*)(wsb + WOFF_SBOX);
    float*          ssc  = (float*)(wsb + WOFF_SSC);
    unsigned short* sid  = (unsigned short*)(wsb + WOFF_SID);

    const int tid = threadIdx.x, lane = tid & 63, seg = tid >> 6;
    const int q = (j << 6) + lane;
    const bool aq = q < V;
    float m = aq ? csc[q] : INFINITY;
    const int Q = (V + 3) >> 2;
    int i0 = seg * Q, i1 = i0 + Q;
    if (i1 > V) i1 = V;
    int r = 0;
#pragma unroll 4
    for (int i = i0; i < i1; ++i) {        // wave-uniform stream -> scalar loads
        float s = csc[i];
        r += (s > m || (s == m && i < q)) ? 1 : 0;
    }
    __shared__ int part[256];
    part[tid] = r;
    __syncthreads();
    if (seg == 0 && aq) {
        int R = part[lane] + part[64 + lane] + part[128 + lane] + part[192 + lane];
        sbox[R] = cbx[q];
        ssc[R]  = m;
        sid[R]  = cid[q];
    }
}

// ========== K3: suppression matrix build for superchunk 0 (stripe k/block) ==========
// Valid for ANY V: rows u<512 only reference columns j<u<512 (greedy triangularity).
__global__ __launch_bounds__(512) void k3_build(unsigned char* __restrict__ ws)
{
#pragma clang fp contract(off)
    const int bx = blockIdx.x;
    const int bc = bx >> 3, k = bx & 7;
    const int V = ((const int*)(ws + WOFF_V))[bc];
    if ((k << 6) >= V) return;
    const int tid = threadIdx.x, lane = tid & 63, w = tid >> 6;
    if (w > k) return;                       // waves beyond stripe idle
    const unsigned char* wsb = ws + (size_t)bc * WS_PER_BC;
    const float2* sbox = (const float2*)(wsb + WOFF_SBOX);
    unsigned long long* mat = (unsigned long long*)(wsb + WOFF_MAT);

    const int u = (k << 6) + lane;           // sorted row this lane builds
    float2 ub = (u < V) ? sbox[u] : make_float2(1e30f, 1e30f);
    float  ul = ub.y - ub.x;
    const float4* sb4 = (const float4*)(sbox + (w << 6));
    unsigned long long word = 0ull;
    for (int jj = 0; jj < 32; ++jj) {        // rolled: compact code
        float4 bp = sb4[jj];
        float in0 = fmaxf(fminf(ub.y, bp.y) - fmaxf(ub.x, bp.x), 0.0f);
        float un0 = (bp.y - bp.x) + ul - in0;
        float io0 = in0 / fmaxf(un0, 1e-12f);
        float in1 = fmaxf(fminf(ub.y, bp.w) - fmaxf(ub.x, bp.z), 0.0f);
        float un1 = (bp.w - bp.z) + ul - in1;
        float io1 = in1 / fmaxf(un1, 1e-12f);
        if (io0 > OVERLAP) word |= (1ull << (2 * jj));
        if (io1 > OVERLAP) word |= (1ull << (2 * jj + 1));
    }
    if (w == k) word &= (1ull << lane) - 1ull;           // diagonal: only j < u
    { int rem = V - (w << 6); if (rem < 64) word &= (1ull << rem) - 1ull; }
    if (u >= V) word = 0ull;
    mat[(TRI(k, w) << 6) + lane] = word;
}

// ==================== K4: greedy fixpoint (V-general) + scatter ====================
__global__ __launch_bounds__(512) void k4_nms(
    float* __restrict__ out, unsigned char* __restrict__ ws)
{
#pragma clang fp contract(off)
    const int tid = threadIdx.x, lane = tid & 63, wid = tid >> 6;
    const int bc = blockIdx.x;
    const int V = ((const int*)(ws + WOFF_V))[bc];
    const unsigned char* wsb = ws + (size_t)bc * WS_PER_BC;
    const float2*             gsbox = (const float2*)(wsb + WOFF_SBOX);
    const float*              gssc  = (const float*)(wsb + WOFF_SSC);
    const unsigned short*     gsid  = (const unsigned short*)(wsb + WOFF_SID);
    const unsigned long long* mat   = (const unsigned long long*)(wsb + WOFF_MAT);

    __shared__ __align__(16) float2 sb[2048];                    // 16 KB
    __shared__ __align__(16) unsigned long long suprowT[8*512];  // 32 KB
    __shared__ unsigned long long keptw[32];
    __shared__ unsigned long long s_deadw[8];

    // stage sorted boxes into LDS; inert pad beyond V
    for (int i = tid; i < 2048; i += 512)
        sb[i] = (i < V) ? gsbox[i] : make_float2(1e30f, 1e30f);
    if (tid < 32) keptw[tid] = 0ull;
    __syncthreads();

    // ---- superchunk 0: wave-0 register fixpoint from K3's global matrix ----
    const int scn0 = (V < 512) ? V : 512;
    if (wid == 0) {
        unsigned long long row[36];
#pragma unroll
        for (int k = 0; k < 8; ++k)
#pragma unroll
            for (int w = 0; w <= k; ++w)
                row[TRI(k, w)] = mat[(TRI(k, w) << 6) + lane];
        unsigned long long kv[8];
#pragma unroll
        for (int w = 0; w < 8; ++w) {
            kv[w] = 0ull;
            if ((w << 6) < scn0) {
                bool dl = false;
#pragma unroll
                for (int w2 = 0; w2 < w; ++w2)
                    dl |= (row[TRI(w, w2)] & kv[w2]) != 0ull;
                const unsigned long long rself = row[TRI(w, w)];
                int rem = scn0 - (w << 6);
                unsigned long long valid =
                    (rem >= 64) ? ~0ull : ((1ull << rem) - 1ull);
                unsigned long long cand = valid & ~__ballot(dl);
                unsigned long long kw = 0ull;
                while (cand) {
                    unsigned long long suppw = __ballot((rself & cand) != 0ull);
                    unsigned long long nk = cand & ~suppw;
                    if (!nk) nk = cand & (~cand + 1ull);  // acyclic: unreachable
                    kw |= nk;
                    unsigned long long ddw = __ballot((rself & nk) != 0ull);
                    cand &= ~(nk | ddw);
                }
                kv[w] = kw;
            }
        }
        if (lane == 0) {
#pragma unroll
            for (int w = 0; w < 8; ++w) keptw[w] = kv[w];
        }
    }
    __syncthreads();

    // ---- superchunks >= 512: in-block build + fixpoint (R7-mono verified path) ----
    for (int s0 = 512; s0 < V; s0 += 512) {
        const int scn = (V - s0 < 512) ? (V - s0) : 512;
        const int i   = tid;
        float2 my = sb[s0 + i];              // pads inert; s0+i <= 2047
        float  ml = my.y - my.x;

        // (a) dead vs kept boxes of earlier superchunks
        bool dead = false;
        const int ew_n = s0 >> 6;
        for (int ew = 0; ew < ew_n; ++ew) {
            unsigned long long kw = keptw[ew];   // wave-uniform
            if (kw) {
                const float4* sb4 = (const float4*)(sb + (ew << 6));
#pragma unroll
                for (int jj = 0; jj < 32; ++jj) {
                    float4 bp = sb4[jj];
                    float in0 = fmaxf(fminf(my.y, bp.y) - fmaxf(my.x, bp.x), 0.0f);
                    float un0 = (bp.y - bp.x) + ml - in0;
                    float io0 = in0 / fmaxf(un0, 1e-12f);
                    float in1 = fmaxf(fminf(my.y, bp.w) - fmaxf(my.x, bp.z), 0.0f);
                    float un1 = (bp.w - bp.z) + ml - in1;
                    float io1 = in1 / fmaxf(un1, 1e-12f);
                    unsigned long long bits = kw >> (2 * jj);
                    dead |= (io0 > OVERLAP) && ((bits & 1ull) != 0ull);
                    dead |= (io1 > OVERLAP) && ((bits & 2ull) != 0ull);
                }
            }
        }
        {
            unsigned long long db = __ballot(dead && (i < scn));
            if (lane == 0) s_deadw[wid] = db;
        }

        // (b) build suprowT for this superchunk, rebalanced round-robin
        {
            int t = 0;
#pragma unroll
            for (int k = 0; k < 8; ++k) {
#pragma unroll
                for (int w = 0; w <= k; ++w, ++t) {
                    if ((t & 7) == wid) {
                        const int u = (k << 6) + lane;
                        float2 ub = sb[s0 + u];
                        float  ul = ub.y - ub.x;
                        const float4* sb4 = (const float4*)(sb + s0 + (w << 6));
                        unsigned long long word = 0ull;
                        if (w == k) {
#pragma unroll
                            for (int jj = 0; jj < 32; ++jj) {
                                float4 bp = sb4[jj];
                                float in0 = fmaxf(fminf(ub.y, bp.y) - fmaxf(ub.x, bp.x), 0.0f);
                                float un0 = (bp.y - bp.x) + ul - in0;
                                float io0 = in0 / fmaxf(un0, 1e-12f);
                                float in1 = fmaxf(fminf(ub.y, bp.w) - fmaxf(ub.x, bp.z), 0.0f);
                                float un1 = (bp.w - bp.z) + ul - in1;
                                float io1 = in1 / fmaxf(un1, 1e-12f);
                                if (io0 > OVERLAP && 2 * jj     < lane) word |= (1ull << (2 * jj));
                                if (io1 > OVERLAP && 2 * jj + 1 < lane) word |= (1ull << (2 * jj + 1));
                            }
                        } else {
#pragma unroll
                            for (int jj = 0; jj < 32; ++jj) {
                                float4 bp = sb4[jj];
                                float in0 = fmaxf(fminf(ub.y, bp.y) - fmaxf(ub.x, bp.x), 0.0f);
                                float un0 = (bp.y - bp.x) + ul - in0;
                                float io0 = in0 / fmaxf(un0, 1e-12f);
                                float in1 = fmaxf(fminf(ub.y, bp.w) - fmaxf(ub.x, bp.z), 0.0f);
                                float un1 = (bp.w - bp.z) + ul - in1;
                                float io1 = in1 / fmaxf(un1, 1e-12f);
                                if (io0 > OVERLAP) word |= (1ull << (2 * jj));
                                if (io1 > OVERLAP) word |= (1ull << (2 * jj + 1));
                            }
                        }
                        suprowT[(w << 9) + u] = word;
                    }
                }
            }
        }
        __syncthreads();

        // (c) wave-0 register fixpoint for this superchunk
        if (wid == 0) {
            unsigned long long row[36];
#pragma unroll
            for (int k = 0; k < 8; ++k)
#pragma unroll
                for (int w = 0; w <= k; ++w)
                    row[TRI(k, w)] = suprowT[(w << 9) + (k << 6) + lane];
            unsigned long long sdead[8];
#pragma unroll
            for (int w = 0; w < 8; ++w) sdead[w] = s_deadw[w];

            unsigned long long kv[8];
#pragma unroll
            for (int w = 0; w < 8; ++w) {
                kv[w] = 0ull;
                if ((w << 6) < scn) {
                    bool dl = ((sdead[w] >> lane) & 1ull) != 0ull;
#pragma unroll
                    for (int w2 = 0; w2 < w; ++w2)
                        dl |= (row[TRI(w, w2)] & kv[w2]) != 0ull;
                    const unsigned long long rself = row[TRI(w, w)];
                    int rem = scn - (w << 6);
                    unsigned long long valid =
                        (rem >= 64) ? ~0ull : ((1ull << rem) - 1ull);
                    unsigned long long cand = valid & ~__ballot(dl);
                    unsigned long long kw = 0ull;
                    while (cand) {
                        unsigned long long suppw = __ballot((rself & cand) != 0ull);
                        unsigned long long nk = cand & ~suppw;
                        if (!nk) nk = cand & (~cand + 1ull);
                        kw |= nk;
                        unsigned long long ddw = __ballot((rself & nk) != 0ull);
                        cand &= ~(nk | ddw);
                    }
                    kv[w] = kw;
                }
            }
            if (lane == 0) {
#pragma unroll
                for (int w = 0; w < 8; ++w) keptw[(s0 >> 6) + w] |= kv[w];
            }
        }
        __syncthreads();
    }

    // ---- scatter kept (in_range applied at output only) ----
    float* outb = out + (size_t)bc * N_ANCHORS * 3;
    for (int r = tid; r < V; r += 512) {
        if ((keptw[r >> 6] >> (r & 63)) & 1ull) {
            float2 bx = sb[r];
            if (bx.x > -10.0f && bx.y < 10.0f) {
                int n = gsid[r];
                float* o = outb + (size_t)n * 3;
                o[0] = bx.x;
                o[1] = bx.y;
                o[2] = gssc[r];
            }
        }
    }
}

// =============== fallback: R7 monolithic kernel (if ws too small) ===============
#define BLOCK 512
#define OFF_CSC   0
#define OFF_CBX   8208
#define OFF_CID   24592
#define OFF_SBOX  0
#define OFF_SSC   16896
#define OFF_SID   25088
#define POOL_SZ   29184

__global__ __launch_bounds__(BLOCK) void det_mono(
    const float* __restrict__ loc, const float* __restrict__ cls,
    const float* __restrict__ defs, float* __restrict__ out)
{
#pragma clang fp contract(off)
    const int tid  = threadIdx.x;
    const int lane = tid & 63;
    const int wid  = tid >> 6;
    const int bc   = blockIdx.x;
    const int b    = bc >> 2;
    const int c    = bc & 3;

    __shared__ __align__(16) unsigned char pool[POOL_SZ];
    __shared__ __align__(16) unsigned long long suprowT[8 * 512];
    __shared__ unsigned long long keptg[32];
    __shared__ unsigned long long s_deadw[8];
    __shared__ int s_wsum[8], s_woff[8], s_V;

    float*          csc  = (float*)(pool + OFF_CSC);
    float2*         cbx  = (float2*)(pool + OFF_CBX);
    unsigned short* cid  = (unsigned short*)(pool + OFF_CID);
    float2*         sbox = (float2*)(pool + OFF_SBOX);
    float*          ssc  = (float*)(pool + OFF_SSC);
    unsigned short* sid  = (unsigned short*)(pool + OFF_SID);

    float* const outb = out + (size_t)bc * N_ANCHORS * 3;
    {
        float4 z4 = make_float4(0.f, 0.f, 0.f, 0.f);
        float4* ob4 = (float4*)outb;
        for (int i = tid; i < (N_ANCHORS * 3) / 4; i += BLOCK) ob4[i] = z4;
    }
    if (tid < 32) keptg[tid] = 0ull;

    const int base = tid * 4;
    float c20[20], l8v[8], d8v[8];
    {
        const float4* cp4 = (const float4*)(cls + ((size_t)b * N_ANCHORS + base) * 5);
#pragma unroll
        for (int q = 0; q < 5; ++q) ((float4*)c20)[q] = cp4[q];
        const float4* lp4 = (const float4*)(loc + ((size_t)b * N_ANCHORS + base) * 2);
        ((float4*)l8v)[0] = lp4[0]; ((float4*)l8v)[1] = lp4[1];
        const float4* dp4 = (const float4*)(defs + (size_t)base * 2);
        ((float4*)d8v)[0] = dp4[0]; ((float4*)d8v)[1] = dp4[1];
    }
    float sc4[4], bs4[4], be4[4];
    int vmask = 0, cnt = 0;
#pragma unroll
    for (int k = 0; k < 4; ++k) {
        float x0 = c20[5*k+0], x1 = c20[5*k+1], x2 = c20[5*k+2],
              x3 = c20[5*k+3], x4 = c20[5*k+4];
        float m  = fmaxf(fmaxf(fmaxf(fmaxf(x0, x1), x2), x3), x4);
        float e0 = expf(x0 - m), e1 = expf(x1 - m), e2 = expf(x2 - m),
              e3 = expf(x3 - m), e4 = expf(x4 - m);
        float sum = e0 + e1 + e2 + e3 + e4;
        float ec  = (c == 0) ? e1 : (c == 1) ? e2 : (c == 2) ? e3 : e4;
        float score = ec / sum;
        float l0 = l8v[2*k], l1 = l8v[2*k+1];
        float d0 = d8v[2*k], d1 = d8v[2*k+1];
        float cc = d0 + l0 * d1;
        float w  = d1 * expf(l1);
        sc4[k] = score;
        bs4[k] = cc - 0.5f * w;
        be4[k] = cc + 0.5f * w;
        if (score > THRESH) { vmask |= (1 << k); cnt++; }
    }

    int inc = cnt;
    for (int d = 1; d < 64; d <<= 1) {
        int v = __shfl_up(inc, d);
        if (lane >= d) inc += v;
    }
    if (lane == 63) s_wsum[wid] = inc;
    __syncthreads();
    if (tid == 0) {
        int o = 0;
        for (int w = 0; w < 8; ++w) { s_woff[w] = o; o += s_wsum[w]; }
        s_V = o;
    }
    __syncthreads();
    {
        int off = s_woff[wid] + (inc - cnt);
#pragma unroll
        for (int k = 0; k < 4; ++k) {
            if (vmask & (1 << k)) {
                csc[off] = sc4[k];
                cbx[off] = make_float2(bs4[k], be4[k]);
                cid[off] = (unsigned short)(base + k);
                off++;
            }
        }
    }
    __syncthreads();
    const int V = s_V;
    const int SCend = ((V + 511) >> 9) << 9;
    if (tid < 4) csc[V + tid] = -INFINITY;
    __syncthreads();

#define RANKCMP(sv, ib, off2, mref, rref)                                   \
    rref += ((sv) > (mref) || ((sv) == (mref) && (ib) + (off2) < pcmp)) ? 1 : 0;
    int rr[4]; float2 rb[4]; float rs[4]; int ridv[4]; int nown = 0;
    if (V <= 512) {
        if (tid < 256) {
            int   p0 = tid, p1 = tid + 256;
            bool  a0 = p0 < V, a1 = p1 < V;
            float m0 = a0 ? csc[p0] : INFINITY;
            float m1 = a1 ? csc[p1] : INFINITY;
            int   r0 = 0, r1 = 0;
            const float4* cs4 = (const float4*)csc;
            const int n4 = (V + 3) >> 2;
            for (int i4 = 0; i4 < n4; ++i4) {
                float4 s4 = cs4[i4];
                int ib = i4 << 2;
                { int pcmp = p0;
                  RANKCMP(s4.x, ib, 0, m0, r0) RANKCMP(s4.y, ib, 1, m0, r0)
                  RANKCMP(s4.z, ib, 2, m0, r0) RANKCMP(s4.w, ib, 3, m0, r0) }
                { int pcmp = p1;
                  RANKCMP(s4.x, ib, 0, m1, r1) RANKCMP(s4.y, ib, 1, m1, r1)
                  RANKCMP(s4.z, ib, 2, m1, r1) RANKCMP(s4.w, ib, 3, m1, r1) }
            }
            if (a0) { rr[nown] = r0; rb[nown] = cbx[p0]; rs[nown] = m0; ridv[nown] = cid[p0]; nown++; }
            if (a1) { rr[nown] = r1; rb[nown] = cbx[p1]; rs[nown] = m1; ridv[nown] = cid[p1]; nown++; }
        }
    } else {
        for (int p = tid; p < V; p += BLOCK) {
            float s = csc[p];
            int r = 0;
            const float4* cs4 = (const float4*)csc;
            const int n4 = (V + 3) >> 2;
            for (int i4 = 0; i4 < n4; ++i4) {
                float4 s4 = cs4[i4];
                int ib = i4 << 2;
                int pcmp = p;
                RANKCMP(s4.x, ib, 0, s, r) RANKCMP(s4.y, ib, 1, s, r)
                RANKCMP(s4.z, ib, 2, s, r) RANKCMP(s4.w, ib, 3, s, r)
            }
            rr[nown] = r; rb[nown] = cbx[p]; rs[nown] = s; ridv[nown] = cid[p]; nown++;
        }
    }
#undef RANKCMP
    __syncthreads();
    for (int q = 0; q < nown; ++q) {
        sbox[rr[q]] = rb[q];
        ssc[rr[q]]  = rs[q];
        sid[rr[q]]  = (unsigned short)ridv[q];
    }
    for (int i = V + tid; i < SCend; i += BLOCK)
        sbox[i] = make_float2(1e30f, 1e30f);
    __syncthreads();

    for (int s0 = 0; s0 < V; s0 += 512) {
        const int scn = (V - s0 < 512) ? (V - s0) : 512;
        const int i   = tid;
        float2 my = sbox[s0 + i];
        float  ml = my.y - my.x;

        bool dead = false;
        const int ew_n = s0 >> 6;
        for (int ew = 0; ew < ew_n; ++ew) {
            unsigned long long kw = keptg[ew];
            if (kw) {
                const float4* sb4 = (const float4*)(sbox + (ew << 6));
#pragma unroll
                for (int jj = 0; jj < 32; ++jj) {
                    float4 bp = sb4[jj];
                    float in0 = fmaxf(fminf(my.y, bp.y) - fmaxf(my.x, bp.x), 0.0f);
                    float un0 = (bp.y - bp.x) + ml - in0;
                    float io0 = in0 / fmaxf(un0, 1e-12f);
                    float in1 = fmaxf(fminf(my.y, bp.w) - fmaxf(my.x, bp.z), 0.0f);
                    float un1 = (bp.w - bp.z) + ml - in1;
                    float io1 = in1 / fmaxf(un1, 1e-12f);
                    unsigned long long bits = kw >> (2 * jj);
                    dead |= (io0 > OVERLAP) && ((bits & 1ull) != 0ull);
                    dead |= (io1 > OVERLAP) && ((bits & 2ull) != 0ull);
                }
            }
        }
        {
            unsigned long long db = __ballot(dead && (i < scn));
            if (lane == 0) s_deadw[wid] = db;
        }

        {
            int t = 0;
#pragma unroll
            for (int k = 0; k < 8; ++k) {
#pragma unroll
                for (int w = 0; w <= k; ++w, ++t) {
                    if ((t & 7) == wid) {
                        const int u = (k << 6) + lane;
                        float2 ub = sbox[s0 + u];
                        float  ul = ub.y - ub.x;
                        const float4* sb4 = (const float4*)(sbox + s0 + (w << 6));
                        unsigned long long word = 0ull;
                        if (w == k) {
#pragma unroll
                            for (int jj = 0; jj < 32; ++jj) {
                                float4 bp = sb4[jj];
                                float in0 = fmaxf(fminf(ub.y, bp.y) - fmaxf(ub.x, bp.x), 0.0f);
                                float un0 = (bp.y - bp.x) + ul - in0;
                                float io0 = in0 / fmaxf(un0, 1e-12f);
                                float in1 = fmaxf(fminf(ub.y, bp.w) - fmaxf(ub.x, bp.z), 0.0f);
                                float un1 = (bp.w - bp.z) + ul - in1;
                                float io1 = in1 / fmaxf(un1, 1e-12f);
                                if (io0 > OVERLAP && 2 * jj     < lane) word |= (1ull << (2 * jj));
                                if (io1 > OVERLAP && 2 * jj + 1 < lane) word |= (1ull << (2 * jj + 1));
                            }
                        } else {
#pragma unroll
                            for (int jj = 0; jj < 32; ++jj) {
                                float4 bp = sb4[jj];
                                float in0 = fmaxf(fminf(ub.y, bp.y) - fmaxf(ub.x, bp.x), 0.0f);
                                float un0 = (bp.y - bp.x) + ul - in0;
                                float io0 = in0 / fmaxf(un0, 1e-12f);
                                float in1 = fmaxf(fminf(ub.y, bp.w) - fmaxf(ub.x, bp.z), 0.0f);
                                float un1 = (bp.w - bp.z) + ul - in1;
                                float io1 = in1 / fmaxf(un1, 1e-12f);
                                if (io0 > OVERLAP) word |= (1ull << (2 * jj));
                                if (io1 > OVERLAP) word |= (1ull << (2 * jj + 1));
                            }
                        }
                        suprowT[(w << 9) + u] = word;
                    }
                }
            }
        }
        __syncthreads();

        if (wid == 0) {
            unsigned long long row[36];
#pragma unroll
            for (int k = 0; k < 8; ++k)
#pragma unroll
                for (int w = 0; w <= k; ++w)
                    row[TRI(k, w)] = suprowT[(w << 9) + (k << 6) + lane];
            unsigned long long sdead[8];
#pragma unroll
            for (int w = 0; w < 8; ++w) sdead[w] = s_deadw[w];

            unsigned long long kv[8];
#pragma unroll
            for (int w = 0; w < 8; ++w) {
                kv[w] = 0ull;
                if ((w << 6) < scn) {
                    bool dl = ((sdead[w] >> lane) & 1ull) != 0ull;
#pragma unroll
                    for (int w2 = 0; w2 < w; ++w2)
                        dl |= (row[TRI(w, w2)] & kv[w2]) != 0ull;
                    const unsigned long long rself = row[TRI(w, w)];
                    int rem = scn - (w << 6);
                    unsigned long long valid =
                        (rem >= 64) ? ~0ull : ((1ull << rem) - 1ull);
                    unsigned long long cand = valid & ~__ballot(dl);
                    unsigned long long kw = 0ull;
                    while (cand) {
                        unsigned long long suppw = __ballot((rself & cand) != 0ull);
                        unsigned long long nk = cand & ~suppw;
                        if (!nk) nk = cand & (~cand + 1ull);
                        kw |= nk;
                        unsigned long long ddw = __ballot((rself & nk) != 0ull);
                        cand &= ~(nk | ddw);
                    }
                    kv[w] = kw;
                }
            }
            if (lane == 0) {
#pragma unroll
                for (int w = 0; w < 8; ++w) keptg[(s0 >> 6) + w] |= kv[w];
            }
        }
        __syncthreads();
    }

    for (int r = tid; r < V; r += BLOCK) {
        if ((keptg[r >> 6] >> (r & 63)) & 1ull) {
            float2 bx = sbox[r];
            if (bx.x > -10.0f && bx.y < 10.0f) {
                int n = sid[r];
                float* o = outb + (size_t)n * 3;
                o[0] = bx.x;
                o[1] = bx.y;
                o[2] = ssc[r];
            }
        }
    }
}

extern "C" void kernel_launch(void* const* d_in, const int* in_sizes, int n_in,
                              void* d_out, int out_size, void* d_ws, size_t ws_size,
                              hipStream_t stream) {
    const float* loc  = (const float*)d_in[0];  // localizations (8,2048,2)
    const float* cls  = (const float*)d_in[1];  // classifications (8,2048,5)
    const float* defs = (const float*)d_in[2];  // localizations_default (2048,2)
    float* out = (float*)d_out;                 // (8,4,2048,3) fp32
    if (ws_size >= WS_NEED) {
        unsigned char* ws = (unsigned char*)d_ws;
        k1_decode<<<NBC, 512, 0, stream>>>(loc, cls, defs, out, ws);
        k2_rank  <<<NBC * 32, 256, 0, stream>>>(ws);
        k3_build <<<NBC * 8, 512, 0, stream>>>(ws);
        k4_nms   <<<NBC, 512, 0, stream>>>(out, ws);
    } else {
        det_mono<<<NBC, BLOCK, 0, stream>>>(loc, cls, defs, out);
    }
}

// Round 11
// 107.574 us; speedup vs baseline: 33.1959x; 1.4020x over previous
//
#include <hip/hip_runtime.h>
#include <math.h>

#define N_ANCHORS 2048
#define THRESH 0.3f
#define OVERLAP 0.5f
#define NBC 32

#define TRI(k, w) ((k) * ((k) + 1) / 2 + (w))   // triangular unit index

// ---- workspace: Vs[32] at byte 0, then per-bc regions ----
#define VS_BYTES   128
#define WOFF_CSC   0        // float[2048]   score, compacted (anchor order)
#define WOFF_CBX   8192     // float2[2048]  box,   compacted
#define WOFF_CID   24576    // ushort[2048]  anchor id, compacted
#define WOFF_SBOX  28672    // float2[2048]  box, sorted order
#define WOFF_SSC   45056    // float[2048]   score, sorted order
#define WOFF_SID   53248    // ushort[2048]  anchor id, sorted order
#define WOFF_MAT   57344    // u64 units of 64: STRIDE1 -> 36 units (sc0); STRIDE2 -> 528 units (full)
#define STRIDE1    75776
#define STRIDE2    327680
#define WS_NEED1   (VS_BYTES + (size_t)NBC * STRIDE1)
#define WS_NEED2   (VS_BYTES + (size_t)NBC * STRIDE2)

// ============================ K1: decode + compact ============================
__global__ __launch_bounds__(512) void k1_decode(
    const float* __restrict__ loc, const float* __restrict__ cls,
    const float* __restrict__ defs, float* __restrict__ out,
    unsigned char* __restrict__ ws, size_t stride)
{
#pragma clang fp contract(off)
    const int tid = threadIdx.x, lane = tid & 63, wid = tid >> 6;
    const int bc = blockIdx.x, b = bc >> 2, c = bc & 3;
    __shared__ int s_wsum[8], s_woff[8];

    float* outb = out + (size_t)bc * N_ANCHORS * 3;
    {
        float4 z4 = make_float4(0.f, 0.f, 0.f, 0.f);
        float4* ob4 = (float4*)outb;
        for (int i = tid; i < (N_ANCHORS * 3) / 4; i += 512) ob4[i] = z4;
    }

    const int base = tid * 4;
    float c20[20], l8v[8], d8v[8];
    {
        const float4* cp4 = (const float4*)(cls + ((size_t)b * N_ANCHORS + base) * 5);
#pragma unroll
        for (int q = 0; q < 5; ++q) ((float4*)c20)[q] = cp4[q];
        const float4* lp4 = (const float4*)(loc + ((size_t)b * N_ANCHORS + base) * 2);
        ((float4*)l8v)[0] = lp4[0]; ((float4*)l8v)[1] = lp4[1];
        const float4* dp4 = (const float4*)(defs + (size_t)base * 2);
        ((float4*)d8v)[0] = dp4[0]; ((float4*)d8v)[1] = dp4[1];
    }
    float sc4[4], bs4[4], be4[4];
    int vmask = 0, cnt = 0;
#pragma unroll
    for (int k = 0; k < 4; ++k) {
        float x0 = c20[5*k+0], x1 = c20[5*k+1], x2 = c20[5*k+2],
              x3 = c20[5*k+3], x4 = c20[5*k+4];
        float m  = fmaxf(fmaxf(fmaxf(fmaxf(x0, x1), x2), x3), x4);
        float e0 = expf(x0 - m), e1 = expf(x1 - m), e2 = expf(x2 - m),
              e3 = expf(x3 - m), e4 = expf(x4 - m);
        float sum = e0 + e1 + e2 + e3 + e4;
        float ec  = (c == 0) ? e1 : (c == 1) ? e2 : (c == 2) ? e3 : e4;
        float score = ec / sum;
        float l0 = l8v[2*k], l1 = l8v[2*k+1];
        float d0 = d8v[2*k], d1 = d8v[2*k+1];
        float cc = d0 + l0 * d1;
        float w  = d1 * expf(l1);
        sc4[k] = score;
        bs4[k] = cc - 0.5f * w;
        be4[k] = cc + 0.5f * w;
        if (score > THRESH) { vmask |= (1 << k); cnt++; }
    }

    int inc = cnt;
    for (int d = 1; d < 64; d <<= 1) {
        int v = __shfl_up(inc, d);
        if (lane >= d) inc += v;
    }
    if (lane == 63) s_wsum[wid] = inc;
    __syncthreads();
    if (tid == 0) {
        int o = 0;
        for (int w = 0; w < 8; ++w) { s_woff[w] = o; o += s_wsum[w]; }
        ((int*)ws)[bc] = o;
    }
    __syncthreads();
    unsigned char* wsb = ws + VS_BYTES + (size_t)bc * stride;
    float*          wcsc = (float*)(wsb + WOFF_CSC);
    float2*         wcbx = (float2*)(wsb + WOFF_CBX);
    unsigned short* wcid = (unsigned short*)(wsb + WOFF_CID);
    int off = s_woff[wid] + (inc - cnt);
#pragma unroll
    for (int k = 0; k < 4; ++k) {
        if (vmask & (1 << k)) {
            wcsc[off] = sc4[k];
            wcbx[off] = make_float2(bs4[k], be4[k]);
            wcid[off] = (unsigned short)(base + k);
            off++;
        }
    }
}

// ===================== K2: counting rank (64 candidates/block) =====================
__global__ __launch_bounds__(256) void k2_rank(unsigned char* __restrict__ ws, size_t stride)
{
    const int bx = blockIdx.x;
    const int bc = bx >> 5, j = bx & 31;
    const int V = ((const int*)ws)[bc];
    if ((j << 6) >= V) return;
    unsigned char* wsb = ws + VS_BYTES + (size_t)bc * stride;
    const float*          csc = (const float*)(wsb + WOFF_CSC);
    const float2*         cbx = (const float2*)(wsb + WOFF_CBX);
    const unsigned short* cid = (const unsigned short*)(wsb + WOFF_CID);
    float2*         sbox = (float2*)(wsb + WOFF_SBOX);
    float*          ssc  = (float*)(wsb + WOFF_SSC);
    unsigned short* sid  = (unsigned short*)(wsb + WOFF_SID);

    const int tid = threadIdx.x, lane = tid & 63, seg = tid >> 6;
    const int q = (j << 6) + lane;
    const bool aq = q < V;
    float m = aq ? csc[q] : INFINITY;
    const int Q = (V + 3) >> 2;
    int i0 = seg * Q, i1 = i0 + Q;
    if (i1 > V) i1 = V;
    int r = 0;
#pragma unroll 4
    for (int i = i0; i < i1; ++i) {
        float s = csc[i];
        r += (s > m || (s == m && i < q)) ? 1 : 0;
    }
    __shared__ int part[256];
    part[tid] = r;
    __syncthreads();
    if (seg == 0 && aq) {
        int R = part[lane] + part[64 + lane] + part[128 + lane] + part[192 + lane];
        sbox[R] = cbx[q];
        ssc[R]  = m;
        sid[R]  = cid[q];
    }
}

// ============ K3-full: FULL triangular suppression matrix (stripe g/block) ============
// Kept-independent: every IoU pair computed here at 1024-block parallelism.
__global__ __launch_bounds__(512) void k3_full(unsigned char* __restrict__ ws)
{
#pragma clang fp contract(off)
    const int bx = blockIdx.x;
    const int bc = bx >> 5, g = bx & 31;
    const int V = ((const int*)ws)[bc];
    if ((g << 6) >= V) return;
    const int tid = threadIdx.x, lane = tid & 63, wid = tid >> 6;
    unsigned char* wsb = ws + VS_BYTES + (size_t)bc * STRIDE2;
    const float2* sbox = (const float2*)(wsb + WOFF_SBOX);
    unsigned long long* mat = (unsigned long long*)(wsb + WOFF_MAT);

    const int u = (g << 6) + lane;
    float2 ub = (u < V) ? sbox[u] : make_float2(1e30f, 1e30f);
    float  ul = ub.y - ub.x;
    for (int w = wid; w <= g; w += 8) {          // words round-robin over 8 waves
        const float4* sb4 = (const float4*)(sbox + (w << 6));
        unsigned long long word = 0ull;
        for (int jj = 0; jj < 32; ++jj) {
            float4 bp = sb4[jj];
            float in0 = fmaxf(fminf(ub.y, bp.y) - fmaxf(ub.x, bp.x), 0.0f);
            float un0 = (bp.y - bp.x) + ul - in0;
            float io0 = in0 / fmaxf(un0, 1e-12f);
            float in1 = fmaxf(fminf(ub.y, bp.w) - fmaxf(ub.x, bp.z), 0.0f);
            float un1 = (bp.w - bp.z) + ul - in1;
            float io1 = in1 / fmaxf(un1, 1e-12f);
            if (io0 > OVERLAP) word |= (1ull << (2 * jj));
            if (io1 > OVERLAP) word |= (1ull << (2 * jj + 1));
        }
        if (w == g) word &= (1ull << lane) - 1ull;       // diagonal: only j < u
        { int rem = V - (w << 6); if (rem < 64) word &= (1ull << rem) - 1ull; }
        if (u >= V) word = 0ull;
        mat[((size_t)TRI(g, w) << 6) + lane] = word;
    }
}

// ========== K4-fix: pure bit-ops whole-V greedy fixpoint (wave 0) + scatter ==========
__global__ __launch_bounds__(512) void k4_fix(
    float* __restrict__ out, unsigned char* __restrict__ ws)
{
    const int tid = threadIdx.x, lane = tid & 63, wid = tid >> 6;
    const int bc = blockIdx.x;
    const int V = ((const int*)ws)[bc];
    const unsigned char* wsb = ws + VS_BYTES + (size_t)bc * STRIDE2;
    const float2*             sbox = (const float2*)(wsb + WOFF_SBOX);
    const float*              ssc  = (const float*)(wsb + WOFF_SSC);
    const unsigned short*     sid  = (const unsigned short*)(wsb + WOFF_SID);
    const unsigned long long* mat  = (const unsigned long long*)(wsb + WOFF_MAT);
    __shared__ unsigned long long s_kv[32];

    if (tid < 32) s_kv[tid] = 0ull;
    __syncthreads();

    const int W = (V + 63) >> 6;
    if (wid == 0) {
        for (int g = 0; g < W; ++g) {
            // box u = 64g+lane dead iff some kept j in an earlier word suppresses it
            unsigned long long dl_or = 0ull;
            for (int w = 0; w < g; ++w) {
                unsigned long long rw = mat[((size_t)TRI(g, w) << 6) + lane];
                dl_or |= rw & s_kv[w];
            }
            unsigned long long rself = mat[((size_t)TRI(g, g) << 6) + lane];
            int rem = V - (g << 6);
            unsigned long long valid = (rem >= 64) ? ~0ull : ((1ull << rem) - 1ull);
            unsigned long long cand = valid & ~__ballot(dl_or != 0ull);
            unsigned long long kw = 0ull;
            while (cand) {                     // in-word greedy levels
                unsigned long long suppw = __ballot((rself & cand) != 0ull);
                unsigned long long nk = cand & ~suppw;
                if (!nk) nk = cand & (~cand + 1ull);   // acyclic: unreachable
                kw |= nk;
                unsigned long long ddw = __ballot((rself & nk) != 0ull);
                cand &= ~(nk | ddw);
            }
            if (lane == 0) s_kv[g] = kw;
        }
    }
    __syncthreads();

    float* outb = out + (size_t)bc * N_ANCHORS * 3;
    for (int r = tid; r < V; r += 512) {
        if ((s_kv[r >> 6] >> (r & 63)) & 1ull) {
            float2 bx = sbox[r];
            if (bx.x > -10.0f && bx.y < 10.0f) {
                int n = sid[r];
                float* o = outb + (size_t)n * 3;
                o[0] = bx.x;
                o[1] = bx.y;
                o[2] = ssc[r];
            }
        }
    }
}

// ========== middle-path kernels (R10, ws in [2.4, 10.5) MB) ==========
__global__ __launch_bounds__(512) void k3_sc0(unsigned char* __restrict__ ws)
{
#pragma clang fp contract(off)
    const int bx = blockIdx.x;
    const int bc = bx >> 3, k = bx & 7;
    const int V = ((const int*)ws)[bc];
    if ((k << 6) >= V) return;
    const int tid = threadIdx.x, lane = tid & 63, w = tid >> 6;
    if (w > k) return;
    unsigned char* wsb = ws + VS_BYTES + (size_t)bc * STRIDE1;
    const float2* sbox = (const float2*)(wsb + WOFF_SBOX);
    unsigned long long* mat = (unsigned long long*)(wsb + WOFF_MAT);

    const int u = (k << 6) + lane;
    float2 ub = (u < V) ? sbox[u] : make_float2(1e30f, 1e30f);
    float  ul = ub.y - ub.x;
    const float4* sb4 = (const float4*)(sbox + (w << 6));
    unsigned long long word = 0ull;
    for (int jj = 0; jj < 32; ++jj) {
        float4 bp = sb4[jj];
        float in0 = fmaxf(fminf(ub.y, bp.y) - fmaxf(ub.x, bp.x), 0.0f);
        float un0 = (bp.y - bp.x) + ul - in0;
        float io0 = in0 / fmaxf(un0, 1e-12f);
        float in1 = fmaxf(fminf(ub.y, bp.w) - fmaxf(ub.x, bp.z), 0.0f);
        float un1 = (bp.w - bp.z) + ul - in1;
        float io1 = in1 / fmaxf(un1, 1e-12f);
        if (io0 > OVERLAP) word |= (1ull << (2 * jj));
        if (io1 > OVERLAP) word |= (1ull << (2 * jj + 1));
    }
    if (w == k) word &= (1ull << lane) - 1ull;
    { int rem = V - (w << 6); if (rem < 64) word &= (1ull << rem) - 1ull; }
    if (u >= V) word = 0ull;
    mat[((size_t)TRI(k, w) << 6) + lane] = word;
}

__global__ __launch_bounds__(512) void k4_blk(
    float* __restrict__ out, unsigned char* __restrict__ ws)
{
#pragma clang fp contract(off)
    const int tid = threadIdx.x, lane = tid & 63, wid = tid >> 6;
    const int bc = blockIdx.x;
    const int V = ((const int*)ws)[bc];
    const unsigned char* wsb = ws + VS_BYTES + (size_t)bc * STRIDE1;
    const float2*             gsbox = (const float2*)(wsb + WOFF_SBOX);
    const float*              gssc  = (const float*)(wsb + WOFF_SSC);
    const unsigned short*     gsid  = (const unsigned short*)(wsb + WOFF_SID);
    const unsigned long long* mat   = (const unsigned long long*)(wsb + WOFF_MAT);

    __shared__ __align__(16) float2 sb[2048];
    __shared__ __align__(16) unsigned long long suprowT[8*512];
    __shared__ unsigned long long keptw[32];
    __shared__ unsigned long long s_deadw[8];

    for (int i = tid; i < 2048; i += 512)
        sb[i] = (i < V) ? gsbox[i] : make_float2(1e30f, 1e30f);
    if (tid < 32) keptw[tid] = 0ull;
    __syncthreads();

    const int scn0 = (V < 512) ? V : 512;
    if (wid == 0) {
        unsigned long long row[36];
#pragma unroll
        for (int k = 0; k < 8; ++k)
#pragma unroll
            for (int w = 0; w <= k; ++w)
                row[TRI(k, w)] = mat[((size_t)TRI(k, w) << 6) + lane];
        unsigned long long kv[8];
#pragma unroll
        for (int w = 0; w < 8; ++w) {
            kv[w] = 0ull;
            if ((w << 6) < scn0) {
                bool dl = false;
#pragma unroll
                for (int w2 = 0; w2 < w; ++w2)
                    dl |= (row[TRI(w, w2)] & kv[w2]) != 0ull;
                const unsigned long long rself = row[TRI(w, w)];
                int rem = scn0 - (w << 6);
                unsigned long long valid = (rem >= 64) ? ~0ull : ((1ull << rem) - 1ull);
                unsigned long long cand = valid & ~__ballot(dl);
                unsigned long long kw = 0ull;
                while (cand) {
                    unsigned long long suppw = __ballot((rself & cand) != 0ull);
                    unsigned long long nk = cand & ~suppw;
                    if (!nk) nk = cand & (~cand + 1ull);
                    kw |= nk;
                    unsigned long long ddw = __ballot((rself & nk) != 0ull);
                    cand &= ~(nk | ddw);
                }
                kv[w] = kw;
            }
        }
        if (lane == 0) {
#pragma unroll
            for (int w = 0; w < 8; ++w) keptw[w] = kv[w];
        }
    }
    __syncthreads();

    for (int s0 = 512; s0 < V; s0 += 512) {
        const int scn = (V - s0 < 512) ? (V - s0) : 512;
        const int i   = tid;
        float2 my = sb[s0 + i];
        float  ml = my.y - my.x;

        bool dead = false;
        const int ew_n = s0 >> 6;
        for (int ew = 0; ew < ew_n; ++ew) {
            unsigned long long kw = keptw[ew];
            if (kw) {
                const float4* sb4 = (const float4*)(sb + (ew << 6));
#pragma unroll
                for (int jj = 0; jj < 32; ++jj) {
                    float4 bp = sb4[jj];
                    float in0 = fmaxf(fminf(my.y, bp.y) - fmaxf(my.x, bp.x), 0.0f);
                    float un0 = (bp.y - bp.x) + ml - in0;
                    float io0 = in0 / fmaxf(un0, 1e-12f);
                    float in1 = fmaxf(fminf(my.y, bp.w) - fmaxf(my.x, bp.z), 0.0f);
                    float un1 = (bp.w - bp.z) + ml - in1;
                    float io1 = in1 / fmaxf(un1, 1e-12f);
                    unsigned long long bits = kw >> (2 * jj);
                    dead |= (io0 > OVERLAP) && ((bits & 1ull) != 0ull);
                    dead |= (io1 > OVERLAP) && ((bits & 2ull) != 0ull);
                }
            }
        }
        {
            unsigned long long db = __ballot(dead && (i < scn));
            if (lane == 0) s_deadw[wid] = db;
        }

        {
            int t = 0;
#pragma unroll
            for (int k = 0; k < 8; ++k) {
#pragma unroll
                for (int w = 0; w <= k; ++w, ++t) {
                    if ((t & 7) == wid) {
                        const int u = (k << 6) + lane;
                        float2 ub = sb[s0 + u];
                        float  ul = ub.y - ub.x;
                        const float4* sb4 = (const float4*)(sb + s0 + (w << 6));
                        unsigned long long word = 0ull;
                        if (w == k) {
#pragma unroll
                            for (int jj = 0; jj < 32; ++jj) {
                                float4 bp = sb4[jj];
                                float in0 = fmaxf(fminf(ub.y, bp.y) - fmaxf(ub.x, bp.x), 0.0f);
                                float un0 = (bp.y - bp.x) + ul - in0;
                                float io0 = in0 / fmaxf(un0, 1e-12f);
                                float in1 = fmaxf(fminf(ub.y, bp.w) - fmaxf(ub.x, bp.z), 0.0f);
                                float un1 = (bp.w - bp.z) + ul - in1;
                                float io1 = in1 / fmaxf(un1, 1e-12f);
                                if (io0 > OVERLAP && 2 * jj     < lane) word |= (1ull << (2 * jj));
                                if (io1 > OVERLAP && 2 * jj + 1 < lane) word |= (1ull << (2 * jj + 1));
                            }
                        } else {
#pragma unroll
                            for (int jj = 0; jj < 32; ++jj) {
                                float4 bp = sb4[jj];
                                float in0 = fmaxf(fminf(ub.y, bp.y) - fmaxf(ub.x, bp.x), 0.0f);
                                float un0 = (bp.y - bp.x) + ul - in0;
                                float io0 = in0 / fmaxf(un0, 1e-12f);
                                float in1 = fmaxf(fminf(ub.y, bp.w) - fmaxf(ub.x, bp.z), 0.0f);
                                float un1 = (bp.w - bp.z) + ul - in1;
                                float io1 = in1 / fmaxf(un1, 1e-12f);
                                if (io0 > OVERLAP) word |= (1ull << (2 * jj));
                                if (io1 > OVERLAP) word |= (1ull << (2 * jj + 1));
                            }
                        }
                        suprowT[(w << 9) + u] = word;
                    }
                }
            }
        }
        __syncthreads();

        if (wid == 0) {
            unsigned long long row[36];
#pragma unroll
            for (int k = 0; k < 8; ++k)
#pragma unroll
                for (int w = 0; w <= k; ++w)
                    row[TRI(k, w)] = suprowT[(w << 9) + (k << 6) + lane];
            unsigned long long sdead[8];
#pragma unroll
            for (int w = 0; w < 8; ++w) sdead[w] = s_deadw[w];

            unsigned long long kv[8];
#pragma unroll
            for (int w = 0; w < 8; ++w) {
                kv[w] = 0ull;
                if ((w << 6) < scn) {
                    bool dl = ((sdead[w] >> lane) & 1ull) != 0ull;
#pragma unroll
                    for (int w2 = 0; w2 < w; ++w2)
                        dl |= (row[TRI(w, w2)] & kv[w2]) != 0ull;
                    const unsigned long long rself = row[TRI(w, w)];
                    int rem = scn - (w << 6);
                    unsigned long long valid = (rem >= 64) ? ~0ull : ((1ull << rem) - 1ull);
                    unsigned long long cand = valid & ~__ballot(dl);
                    unsigned long long kw = 0ull;
                    while (cand) {
                        unsigned long long suppw = __ballot((rself & cand) != 0ull);
                        unsigned long long nk = cand & ~suppw;
                        if (!nk) nk = cand & (~cand + 1ull);
                        kw |= nk;
                        unsigned long long ddw = __ballot((rself & nk) != 0ull);
                        cand &= ~(nk | ddw);
                    }
                    kv[w] = kw;
                }
            }
            if (lane == 0) {
#pragma unroll
                for (int w = 0; w < 8; ++w) keptw[(s0 >> 6) + w] |= kv[w];
            }
        }
        __syncthreads();
    }

    float* outb = out + (size_t)bc * N_ANCHORS * 3;
    for (int r = tid; r < V; r += 512) {
        if ((keptw[r >> 6] >> (r & 63)) & 1ull) {
            float2 bx = sb[r];
            if (bx.x > -10.0f && bx.y < 10.0f) {
                int n = gsid[r];
                float* o = outb + (size_t)n * 3;
                o[0] = bx.x;
                o[1] = bx.y;
                o[2] = gssc[r];
            }
        }
    }
}

// =============== last-resort fallback: monolithic (tiny ws) ===============
#define BLOCK 512
#define OFF_CSC   0
#define OFF_CBX   8208
#define OFF_CID   24592
#define OFF_SBOX  0
#define OFF_SSC   16896
#define OFF_SID   25088
#define POOL_SZ   29184

__global__ __launch_bounds__(BLOCK) void det_mono(
    const float* __restrict__ loc, const float* __restrict__ cls,
    const float* __restrict__ defs, float* __restrict__ out)
{
#pragma clang fp contract(off)
    const int tid  = threadIdx.x;
    const int lane = tid & 63;
    const int wid  = tid >> 6;
    const int bc   = blockIdx.x;
    const int b    = bc >> 2;
    const int c    = bc & 3;

    __shared__ __align__(16) unsigned char pool[POOL_SZ];
    __shared__ __align__(16) unsigned long long suprowT[8 * 512];
    __shared__ unsigned long long keptg[32];
    __shared__ unsigned long long s_deadw[8];
    __shared__ int s_wsum[8], s_woff[8], s_V;

    float*          csc  = (float*)(pool + OFF_CSC);
    float2*         cbx  = (float2*)(pool + OFF_CBX);
    unsigned short* cid  = (unsigned short*)(pool + OFF_CID);
    float2*         sbox = (float2*)(pool + OFF_SBOX);
    float*          ssc  = (float*)(pool + OFF_SSC);
    unsigned short* sid  = (unsigned short*)(pool + OFF_SID);

    float* const outb = out + (size_t)bc * N_ANCHORS * 3;
    {
        float4 z4 = make_float4(0.f, 0.f, 0.f, 0.f);
        float4* ob4 = (float4*)outb;
        for (int i = tid; i < (N_ANCHORS * 3) / 4; i += BLOCK) ob4[i] = z4;
    }
    if (tid < 32) keptg[tid] = 0ull;

    const int base = tid * 4;
    float c20[20], l8v[8], d8v[8];
    {
        const float4* cp4 = (const float4*)(cls + ((size_t)b * N_ANCHORS + base) * 5);
#pragma unroll
        for (int q = 0; q < 5; ++q) ((float4*)c20)[q] = cp4[q];
        const float4* lp4 = (const float4*)(loc + ((size_t)b * N_ANCHORS + base) * 2);
        ((float4*)l8v)[0] = lp4[0]; ((float4*)l8v)[1] = lp4[1];
        const float4* dp4 = (const float4*)(defs + (size_t)base * 2);
        ((float4*)d8v)[0] = dp4[0]; ((float4*)d8v)[1] = dp4[1];
    }
    float sc4[4], bs4[4], be4[4];
    int vmask = 0, cnt = 0;
#pragma unroll
    for (int k = 0; k < 4; ++k) {
        float x0 = c20[5*k+0], x1 = c20[5*k+1], x2 = c20[5*k+2],
              x3 = c20[5*k+3], x4 = c20[5*k+4];
        float m  = fmaxf(fmaxf(fmaxf(fmaxf(x0, x1), x2), x3), x4);
        float e0 = expf(x0 - m), e1 = expf(x1 - m), e2 = expf(x2 - m),
              e3 = expf(x3 - m), e4 = expf(x4 - m);
        float sum = e0 + e1 + e2 + e3 + e4;
        float ec  = (c == 0) ? e1 : (c == 1) ? e2 : (c == 2) ? e3 : e4;
        float score = ec / sum;
        float l0 = l8v[2*k], l1 = l8v[2*k+1];
        float d0 = d8v[2*k], d1 = d8v[2*k+1];
        float cc = d0 + l0 * d1;
        float w  = d1 * expf(l1);
        sc4[k] = score;
        bs4[k] = cc - 0.5f * w;
        be4[k] = cc + 0.5f * w;
        if (score > THRESH) { vmask |= (1 << k); cnt++; }
    }

    int inc = cnt;
    for (int d = 1; d < 64; d <<= 1) {
        int v = __shfl_up(inc, d);
        if (lane >= d) inc += v;
    }
    if (lane == 63) s_wsum[wid] = inc;
    __syncthreads();
    if (tid == 0) {
        int o = 0;
        for (int w = 0; w < 8; ++w) { s_woff[w] = o; o += s_wsum[w]; }
        s_V = o;
    }
    __syncthreads();
    {
        int off = s_woff[wid] + (inc - cnt);
#pragma unroll
        for (int k = 0; k < 4; ++k) {
            if (vmask & (1 << k)) {
                csc[off] = sc4[k];
                cbx[off] = make_float2(bs4[k], be4[k]);
                cid[off] = (unsigned short)(base + k);
                off++;
            }
        }
    }
    __syncthreads();
    const int V = s_V;
    const int SCend = ((V + 511) >> 9) << 9;
    if (tid < 4) csc[V + tid] = -INFINITY;
    __syncthreads();

#define RANKCMP(sv, ib, off2, mref, rref)                                   \
    rref += ((sv) > (mref) || ((sv) == (mref) && (ib) + (off2) < pcmp)) ? 1 : 0;
    int rr[4]; float2 rb[4]; float rs[4]; int ridv[4]; int nown = 0;
    if (V <= 512) {
        if (tid < 256) {
            int   p0 = tid, p1 = tid + 256;
            bool  a0 = p0 < V, a1 = p1 < V;
            float m0 = a0 ? csc[p0] : INFINITY;
            float m1 = a1 ? csc[p1] : INFINITY;
            int   r0 = 0, r1 = 0;
            const float4* cs4 = (const float4*)csc;
            const int n4 = (V + 3) >> 2;
            for (int i4 = 0; i4 < n4; ++i4) {
                float4 s4 = cs4[i4];
                int ib = i4 << 2;
                { int pcmp = p0;
                  RANKCMP(s4.x, ib, 0, m0, r0) RANKCMP(s4.y, ib, 1, m0, r0)
                  RANKCMP(s4.z, ib, 2, m0, r0) RANKCMP(s4.w, ib, 3, m0, r0) }
                { int pcmp = p1;
                  RANKCMP(s4.x, ib, 0, m1, r1) RANKCMP(s4.y, ib, 1, m1, r1)
                  RANKCMP(s4.z, ib, 2, m1, r1) RANKCMP(s4.w, ib, 3, m1, r1) }
            }
            if (a0) { rr[nown] = r0; rb[nown] = cbx[p0]; rs[nown] = m0; ridv[nown] = cid[p0]; nown++; }
            if (a1) { rr[nown] = r1; rb[nown] = cbx[p1]; rs[nown] = m1; ridv[nown] = cid[p1]; nown++; }
        }
    } else {
        for (int p = tid; p < V; p += BLOCK) {
            float s = csc[p];
            int r = 0;
            const float4* cs4 = (const float4*)csc;
            const int n4 = (V + 3) >> 2;
            for (int i4 = 0; i4 < n4; ++i4) {
                float4 s4 = cs4[i4];
                int ib = i4 << 2;
                int pcmp = p;
                RANKCMP(s4.x, ib, 0, s, r) RANKCMP(s4.y, ib, 1, s, r)
                RANKCMP(s4.z, ib, 2, s, r) RANKCMP(s4.w, ib, 3, s, r)
            }
            rr[nown] = r; rb[nown] = cbx[p]; rs[nown] = s; ridv[nown] = cid[p]; nown++;
        }
    }
#undef RANKCMP
    __syncthreads();
    for (int q = 0; q < nown; ++q) {
        sbox[rr[q]] = rb[q];
        ssc[rr[q]]  = rs[q];
        sid[rr[q]]  = (unsigned short)ridv[q];
    }
    for (int i = V + tid; i < SCend; i += BLOCK)
        sbox[i] = make_float2(1e30f, 1e30f);
    __syncthreads();

    for (int s0 = 0; s0 < V; s0 += 512) {
        const int scn = (V - s0 < 512) ? (V - s0) : 512;
        const int i   = tid;
        float2 my = sbox[s0 + i];
        float  ml = my.y - my.x;

        bool dead = false;
        const int ew_n = s0 >> 6;
        for (int ew = 0; ew < ew_n; ++ew) {
            unsigned long long kw = keptg[ew];
            if (kw) {
                const float4* sb4 = (const float4*)(sbox + (ew << 6));
#pragma unroll
                for (int jj = 0; jj < 32; ++jj) {
                    float4 bp = sb4[jj];
                    float in0 = fmaxf(fminf(my.y, bp.y) - fmaxf(my.x, bp.x), 0.0f);
                    float un0 = (bp.y - bp.x) + ml - in0;
                    float io0 = in0 / fmaxf(un0, 1e-12f);
                    float in1 = fmaxf(fminf(my.y, bp.w) - fmaxf(my.x, bp.z), 0.0f);
                    float un1 = (bp.w - bp.z) + ml - in1;
                    float io1 = in1 / fmaxf(un1, 1e-12f);
                    unsigned long long bits = kw >> (2 * jj);
                    dead |= (io0 > OVERLAP) && ((bits & 1ull) != 0ull);
                    dead |= (io1 > OVERLAP) && ((bits & 2ull) != 0ull);
                }
            }
        }
        {
            unsigned long long db = __ballot(dead && (i < scn));
            if (lane == 0) s_deadw[wid] = db;
        }

        {
            int t = 0;
#pragma unroll
            for (int k = 0; k < 8; ++k) {
#pragma unroll
                for (int w = 0; w <= k; ++w, ++t) {
                    if ((t & 7) == wid) {
                        const int u = (k << 6) + lane;
                        float2 ub = sbox[s0 + u];
                        float  ul = ub.y - ub.x;
                        const float4* sb4 = (const float4*)(sbox + s0 + (w << 6));
                        unsigned long long word = 0ull;
                        if (w == k) {
#pragma unroll
                            for (int jj = 0; jj < 32; ++jj) {
                                float4 bp = sb4[jj];
                                float in0 = fmaxf(fminf(ub.y, bp.y) - fmaxf(ub.x, bp.x), 0.0f);
                                float un0 = (bp.y - bp.x) + ul - in0;
                                float io0 = in0 / fmaxf(un0, 1e-12f);
                                float in1 = fmaxf(fminf(ub.y, bp.w) - fmaxf(ub.x, bp.z), 0.0f);
                                float un1 = (bp.w - bp.z) + ul - in1;
                                float io1 = in1 / fmaxf(un1, 1e-12f);
                                if (io0 > OVERLAP && 2 * jj     < lane) word |= (1ull << (2 * jj));
                                if (io1 > OVERLAP && 2 * jj + 1 < lane) word |= (1ull << (2 * jj + 1));
                            }
                        } else {
#pragma unroll
                            for (int jj = 0; jj < 32; ++jj) {
                                float4 bp = sb4[jj];
                                float in0 = fmaxf(fminf(ub.y, bp.y) - fmaxf(ub.x, bp.x), 0.0f);
                                float un0 = (bp.y - bp.x) + ul - in0;
                                float io0 = in0 / fmaxf(un0, 1e-12f);
                                float in1 = fmaxf(fminf(ub.y, bp.w) - fmaxf(ub.x, bp.z), 0.0f);
                                float un1 = (bp.w - bp.z) + ul - in1;
                                float io1 = in1 / fmaxf(un1, 1e-12f);
                                if (io0 > OVERLAP) word |= (1ull << (2 * jj));
                                if (io1 > OVERLAP) word |= (1ull << (2 * jj + 1));
                            }
                        }
                        suprowT[(w << 9) + u] = word;
                    }
                }
            }
        }
        __syncthreads();

        if (wid == 0) {
            unsigned long long row[36];
#pragma unroll
            for (int k = 0; k < 8; ++k)
#pragma unroll
                for (int w = 0; w <= k; ++w)
                    row[TRI(k, w)] = suprowT[(w << 9) + (k << 6) + lane];
            unsigned long long sdead[8];
#pragma unroll
            for (int w = 0; w < 8; ++w) sdead[w] = s_deadw[w];

            unsigned long long kv[8];
#pragma unroll
            for (int w = 0; w < 8; ++w) {
                kv[w] = 0ull;
                if ((w << 6) < scn) {
                    bool dl = ((sdead[w] >> lane) & 1ull) != 0ull;
#pragma unroll
                    for (int w2 = 0; w2 < w; ++w2)
                        dl |= (row[TRI(w, w2)] & kv[w2]) != 0ull;
                    const unsigned long long rself = row[TRI(w, w)];
                    int rem = scn - (w << 6);
                    unsigned long long valid = (rem >= 64) ? ~0ull : ((1ull << rem) - 1ull);
                    unsigned long long cand = valid & ~__ballot(dl);
                    unsigned long long kw = 0ull;
                    while (cand) {
                        unsigned long long suppw = __ballot((rself & cand) != 0ull);
                        unsigned long long nk = cand & ~suppw;
                        if (!nk) nk = cand & (~cand + 1ull);
                        kw |= nk;
                        unsigned long long ddw = __ballot((rself & nk) != 0ull);
                        cand &= ~(nk | ddw);
                    }
                    kv[w] = kw;
                }
            }
            if (lane == 0) {
#pragma unroll
                for (int w = 0; w < 8; ++w) keptg[(s0 >> 6) + w] |= kv[w];
            }
        }
        __syncthreads();
    }

    for (int r = tid; r < V; r += BLOCK) {
        if ((keptg[r >> 6] >> (r & 63)) & 1ull) {
            float2 bx = sbox[r];
            if (bx.x > -10.0f && bx.y < 10.0f) {
                int n = sid[r];
                float* o = outb + (size_t)n * 3;
                o[0] = bx.x;
                o[1] = bx.y;
                o[2] = ssc[r];
            }
        }
    }
}

extern "C" void kernel_launch(void* const* d_in, const int* in_sizes, int n_in,
                              void* d_out, int out_size, void* d_ws, size_t ws_size,
                              hipStream_t stream) {
    const float* loc  = (const float*)d_in[0];  // localizations (8,2048,2)
    const float* cls  = (const float*)d_in[1];  // classifications (8,2048,5)
    const float* defs = (const float*)d_in[2];  // localizations_default (2048,2)
    float* out = (float*)d_out;                 // (8,4,2048,3) fp32
    if (ws_size >= WS_NEED2) {
        unsigned char* ws = (unsigned char*)d_ws;
        k1_decode<<<NBC, 512, 0, stream>>>(loc, cls, defs, out, ws, (size_t)STRIDE2);
        k2_rank  <<<NBC * 32, 256, 0, stream>>>(ws, (size_t)STRIDE2);
        k3_full  <<<NBC * 32, 512, 0, stream>>>(ws);
        k4_fix   <<<NBC, 512, 0, stream>>>(out, ws);
    } else if (ws_size >= WS_NEED1) {
        unsigned char* ws = (unsigned char*)d_ws;
        k1_decode<<<NBC, 512, 0, stream>>>(loc, cls, defs, out, ws, (size_t)STRIDE1);
        k2_rank  <<<NBC * 32, 256, 0, stream>>>(ws, (size_t)STRIDE1);
        k3_sc0   <<<NBC * 8, 512, 0, stream>>>(ws);
        k4_blk   <<<NBC, 512, 0, stream>>>(out, ws);
    } else {
        det_mono<<<NBC, BLOCK, 0, stream>>>(loc, cls, defs, out);
    }
}